// Round 11
// baseline (138.496 us; speedup 1.0000x reference)
//
#include <hip/hip_runtime.h>
#include <hip/hip_bf16.h>

typedef __attribute__((ext_vector_type(8))) short short8;
typedef __attribute__((ext_vector_type(4))) float f32x4;

#define REP_P 16   // DIAGNOSTIC reps: surface kp in rocprof top-5 (>40us fills)
#define REP_Q 8    // DIAGNOSTIC reps: surface kq in rocprof top-5

// bf16 truncation (round-toward-zero). Safe: s = ||z3||^2 cancels exactly in
// out = s*d / max(s*sqrt(n1*n2), eps); only d,n1,n2 (pure f32) reach out.
__device__ __forceinline__ unsigned int bfhi(float f) {
    return __builtin_bit_cast(unsigned int, f);
}
__device__ __forceinline__ unsigned int pack2(float lo, float hi) {
    return (bfhi(lo) >> 16) | (bfhi(hi) & 0xffff0000u);
}
__device__ __forceinline__ short8 pack_bf8(float4 a, float4 b) {
    uint4 u;
    u.x = pack2(a.x, a.y);
    u.y = pack2(a.z, a.w);
    u.z = pack2(b.x, b.y);
    u.w = pack2(b.z, b.w);
    return __builtin_bit_cast(short8, u);
}

// KP: pure streaming reduce. 256 blocks x 512 thr; wave w, half-wave hl owns
// row row0 + 2w + hl. 12 float4/lane issued up-front (12 KB/wave in flight).
// wsf: d@0, n1@4096, n2@8192.
__global__ __launch_bounds__(512, 4) void kp(
    const float* __restrict__ X, float* __restrict__ wsf)
{
    const int tid  = threadIdx.x;
    const int wid  = tid >> 6;
    const int lane = tid & 63;
    const int hl   = lane >> 5, ln = lane & 31;
    const int row0 = (int)blockIdx.x * 16;
    const int prow = row0 + 2 * wid + hl;
    const float4* b4 = (const float4*)(X + (size_t)prow * 2304);

    for (int rep = 0; rep < REP_P; ++rep) {
        asm volatile("" ::: "memory");   // defeat cross-rep CSE: force reloads
        float4 p1[6], p2[6];
#pragma unroll
        for (int m = 0; m < 6; ++m) p1[m] = b4[192 + ln + 32 * m];
#pragma unroll
        for (int m = 0; m < 6; ++m) p2[m] = b4[384 + ln + 32 * m];
        float dd = 0.f, aa = 0.f, bb = 0.f;
#pragma unroll
        for (int m = 0; m < 6; ++m) {
            float4 x = p1[m], y = p2[m];
            dd += x.x * y.x + x.y * y.y + x.z * y.z + x.w * y.w;
            aa += x.x * x.x + x.y * x.y + x.z * x.z + x.w * x.w;
            bb += y.x * y.x + y.y * y.y + y.z * y.z + y.w * y.w;
        }
#pragma unroll
        for (int m = 1; m < 32; m <<= 1) {
            dd += __shfl_xor(dd, m);
            aa += __shfl_xor(aa, m);
            bb += __shfl_xor(bb, m);
        }
        if (ln == 0) {
            wsf[prow]        = dd;
            wsf[4096 + prow] = aa;
            wsf[8192 + prow] = bb;
        }
    }
}

// KQ: MLP + combine. 256 blocks x 512 thr, 16 rows/block.
// Stage Xq -> LDS bf16 (XOR-swizzled); GEMM1 (N=128, depth-4 f32 W1 pipeline,
// in-register bf16 pack); GEMM2/3; s=||z3||^2; combine with wsf -> out.
__global__ __launch_bounds__(512, 4) void kq(
    const float* __restrict__ X,
    const float* __restrict__ W1, const float* __restrict__ b1,
    const float* __restrict__ W2, const float* __restrict__ b2,
    const float* __restrict__ W3, const float* __restrict__ b3,
    const float* __restrict__ wsf, float* __restrict__ out)
{
    __shared__ __align__(16) char xq[16 * 1536];
    __shared__ __align__(16) unsigned short z1[16][136];
    __shared__ __align__(16) unsigned short z2[16][72];
    __shared__ float sred[2][16];

    const int tid  = threadIdx.x;
    const int wid  = tid >> 6;
    const int lane = tid & 63;
    const int l15  = lane & 15;
    const int l4   = lane >> 4;
    const int row0 = (int)blockIdx.x * 16;

    for (int rep = 0; rep < REP_Q; ++rep) {
        asm volatile("" ::: "memory");   // defeat cross-rep CSE
        // ---- stage Xq ----
        {
            float4 q[6];
            int qr[3], qc[3];
#pragma unroll
            for (int j = 0; j < 3; ++j) {
                int ci = tid + 512 * j;
                int r  = ci / 96;
                int cc = ci - r * 96;
                qr[j] = r; qc[j] = cc;
                const float* p = X + (size_t)(row0 + r) * 2304 + cc * 8;
                q[2 * j]     = *(const float4*)(p);
                q[2 * j + 1] = *(const float4*)(p + 4);
            }
#pragma unroll
            for (int j = 0; j < 3; ++j) {
                uint4 u;
                u.x = pack2(q[2 * j].x,     q[2 * j].y);
                u.y = pack2(q[2 * j].z,     q[2 * j].w);
                u.z = pack2(q[2 * j + 1].x, q[2 * j + 1].y);
                u.w = pack2(q[2 * j + 1].z, q[2 * j + 1].w);
                int byteoff = (qr[j] * 1536 + qc[j] * 16) ^ ((qr[j] & 7) << 4);
                *(uint4*)(xq + byteoff) = u;
            }
        }
        __syncthreads();

        // ---- GEMM1 ----
        {
            f32x4 acc = {0.f, 0.f, 0.f, 0.f};
            const float* bp = W1 + (size_t)(16 * wid + l15) * 768 + l4 * 8;
            const int abase = l15 * 1536;
            const int aswz  = (l15 & 7) << 4;
            float4 wa[4], wb[4];
#pragma unroll
            for (int i = 0; i < 4; ++i) {
                wa[i] = *(const float4*)(bp + i * 32);
                wb[i] = *(const float4*)(bp + i * 32 + 4);
            }
#pragma unroll
            for (int it = 0; it < 24; ++it) {
                const int k0 = it * 32;
                const int slot = it & 3;
                short8 b = pack_bf8(wa[slot], wb[slot]);
                short8 a = *(const short8*)(xq + ((abase + (k0 + l4 * 8) * 2) ^ aswz));
                acc = __builtin_amdgcn_mfma_f32_16x16x32_bf16(a, b, acc, 0, 0, 0);
                if (it < 20) {
                    wa[slot] = *(const float4*)(bp + k0 + 128);
                    wb[slot] = *(const float4*)(bp + k0 + 128 + 4);
                }
            }
            float bv = b1[16 * wid + l15];
#pragma unroll
            for (int r = 0; r < 4; ++r) {
                float v = fmaxf(acc[r] + bv, 0.f);
                z1[4 * l4 + r][16 * wid + l15] = (unsigned short)(bfhi(v) >> 16);
            }
        }
        __syncthreads();

        // ---- GEMM2 (waves 0-3) ----
        if (wid < 4) {
            f32x4 acc = {0.f, 0.f, 0.f, 0.f};
            const float* bp = W2 + (size_t)(16 * wid + l15) * 128 + l4 * 8;
#pragma unroll
            for (int ks = 0; ks < 4; ++ks) {
                short8 b = pack_bf8(*(const float4*)(bp + ks * 32),
                                    *(const float4*)(bp + ks * 32 + 4));
                short8 a = *(const short8*)&z1[l15][ks * 32 + l4 * 8];
                acc = __builtin_amdgcn_mfma_f32_16x16x32_bf16(a, b, acc, 0, 0, 0);
            }
            float bv = b2[16 * wid + l15];
#pragma unroll
            for (int r = 0; r < 4; ++r) {
                float v = fmaxf(acc[r] + bv, 0.f);
                z2[4 * l4 + r][16 * wid + l15] = (unsigned short)(bfhi(v) >> 16);
            }
        }
        __syncthreads();

        // ---- GEMM3 + s (waves 0-1) ----
        if (wid < 2) {
            f32x4 acc = {0.f, 0.f, 0.f, 0.f};
            const float* bp = W3 + (size_t)(16 * wid + l15) * 64 + l4 * 8;
#pragma unroll
            for (int ks = 0; ks < 2; ++ks) {
                short8 b = pack_bf8(*(const float4*)(bp + ks * 32),
                                    *(const float4*)(bp + ks * 32 + 4));
                short8 a = *(const short8*)&z2[l15][ks * 32 + l4 * 8];
                acc = __builtin_amdgcn_mfma_f32_16x16x32_bf16(a, b, acc, 0, 0, 0);
            }
            float bv = b3[16 * wid + l15];
            float sv[4];
#pragma unroll
            for (int r = 0; r < 4; ++r) {
                float v = fmaxf(acc[r] + bv, 0.f);
                sv[r] = v * v;
            }
#pragma unroll
            for (int m = 1; m < 16; m <<= 1)
#pragma unroll
                for (int r = 0; r < 4; ++r) sv[r] += __shfl_xor(sv[r], m);
            if (l15 == 0)
#pragma unroll
                for (int r = 0; r < 4; ++r) sred[wid][4 * l4 + r] = sv[r];
        }
        __syncthreads();

        // ---- combine ----
        if (tid < 16) {
            int row   = row0 + tid;
            float s   = sred[0][tid] + sred[1][tid];
            float den = fmaxf(s * sqrtf(wsf[4096 + row] * wsf[8192 + row]), 1e-8f);
            out[row]  = (s * wsf[row]) / den;
        }
        __syncthreads();
    }
}

extern "C" void kernel_launch(void* const* d_in, const int* in_sizes, int n_in,
                              void* d_out, int out_size, void* d_ws, size_t ws_size,
                              hipStream_t stream)
{
    (void)in_sizes; (void)n_in; (void)out_size; (void)ws_size;
    const float* X  = (const float*)d_in[0];
    const float* W1 = (const float*)d_in[1];
    const float* b1 = (const float*)d_in[2];
    const float* W2 = (const float*)d_in[3];
    const float* b2 = (const float*)d_in[4];
    const float* W3 = (const float*)d_in[5];
    const float* b3 = (const float*)d_in[6];

    float* wsf = (float*)d_ws;   // d@0, n1@4096, n2@8192

    kp<<<dim3(256), dim3(512), 0, stream>>>(X, wsf);
    kq<<<dim3(256), dim3(512), 0, stream>>>(X, W1, b1, W2, b2, W3, b3,
                                            wsf, (float*)d_out);
}

// Round 12
// 23.893 us; speedup vs baseline: 5.7964x; 5.7964x over previous
//
#include <hip/hip_runtime.h>
#include <hip/hip_bf16.h>

typedef __attribute__((ext_vector_type(8))) short short8;
typedef __attribute__((ext_vector_type(4))) float f32x4;

// bf16 truncation (round-toward-zero). Safe: s = ||z3||^2 cancels exactly in
// out = s*d / max(s*sqrt(n1*n2), eps); only d,n1,n2 (pure f32) reach out.
__device__ __forceinline__ unsigned int bfhi(float f) {
    return __builtin_bit_cast(unsigned int, f);
}
__device__ __forceinline__ unsigned int pack2(float lo, float hi) {
    return (bfhi(lo) >> 16) | (bfhi(hi) & 0xffff0000u);
}

// K0: convert W1/W2/W3 f32 -> bf16 into ws (vectorized x4).
// ushort layout: W1b @ 0 (98304), W2b @ 98304 (8192), W3b @ 106496 (2048).
__global__ __launch_bounds__(256) void cvt_weights(
    const float* __restrict__ W1, const float* __restrict__ W2,
    const float* __restrict__ W3, unsigned short* __restrict__ wsb)
{
    int i4 = (blockIdx.x * 256 + threadIdx.x) * 4;
    const float* src;
    int off;
    if (i4 < 98304)       { src = W1; off = 0; }
    else if (i4 < 106496) { src = W2; off = 98304; }
    else                  { src = W3; off = 106496; }
    float4 v = *(const float4*)(src + (i4 - off));
    uint2 u;
    u.x = pack2(v.x, v.y);
    u.y = pack2(v.z, v.w);
    *(uint2*)&wsb[i4] = u;
}

// K1: heterogeneous. 384 blocks x 512 threads, LDS ~62KB -> 2 blocks/CU.
//   bid 0..127  (Q): 32 rows. K-tiled (3x256) Xq -> LDS bf16 (XOR-swizzled);
//                    GEMM1 M=32,N=128,K=768: wave w owns 16 cols, per k-step
//                    1 bf16 B-load (depth-4 rotation) + 2 LDS a-reads + 2 MFMA.
//                    W1 traffic: 128 blocks x 196KB = 25 MB L2 total.
//                    GEMM2 (8 waves), GEMM3 (4 waves), s=||z3||^2 -> wsf.
//   bid 128..383 (P): 16 rows (half-wave = row): 12 float4/lane up-front,
//                    butterfly-reduce d, n1, n2 -> wsf.
// wsf (f32): d@0, n1@4096, n2@8192, s@12288. wsb (ushort) at wsf+16384.
__global__ __launch_bounds__(512, 4) void pq_kernel(
    const float* __restrict__ X,
    const unsigned short* __restrict__ wsb,
    const float* __restrict__ b1,
    const float* __restrict__ b2,
    const float* __restrict__ b3,
    float* __restrict__ wsf)
{
    __shared__ __align__(16) char xq[32 * 1536];          // 32x768 bf16, XOR-swizzled
    __shared__ __align__(16) unsigned short z1[32][136];
    __shared__ __align__(16) unsigned short z2[32][72];
    __shared__ float sred[2][32];

    const int tid  = threadIdx.x;
    const int wid  = tid >> 6;
    const int lane = tid & 63;
    const int l15  = lane & 15;
    const int l4   = lane >> 4;

    if (blockIdx.x >= 128) {
        // ================= P path =================
        const int row = (int)(blockIdx.x - 128) * 16 + 2 * wid + (lane >> 5);
        const int ln  = lane & 31;
        const float4* b4 = (const float4*)(X + (size_t)row * 2304);
        float4 p1[6], p2[6];
#pragma unroll
        for (int m = 0; m < 6; ++m) p1[m] = b4[192 + ln + 32 * m];
#pragma unroll
        for (int m = 0; m < 6; ++m) p2[m] = b4[384 + ln + 32 * m];
        float dd = 0.f, aa = 0.f, bb = 0.f;
#pragma unroll
        for (int m = 0; m < 6; ++m) {
            float4 x = p1[m], y = p2[m];
            dd += x.x * y.x + x.y * y.y + x.z * y.z + x.w * y.w;
            aa += x.x * x.x + x.y * x.y + x.z * x.z + x.w * x.w;
            bb += y.x * y.x + y.y * y.y + y.z * y.z + y.w * y.w;
        }
#pragma unroll
        for (int m = 1; m < 32; m <<= 1) {
            dd += __shfl_xor(dd, m);
            aa += __shfl_xor(aa, m);
            bb += __shfl_xor(bb, m);
        }
        if (ln == 0) {
            wsf[row]        = dd;
            wsf[4096 + row] = aa;
            wsf[8192 + row] = bb;
        }
        return;
    }

    // ================= Q path =================
    const int row0 = (int)blockIdx.x * 32;
    const unsigned short* W1b = wsb;
    const unsigned short* W2b = wsb + 98304;
    const unsigned short* W3b = wsb + 106496;

    // ---- GEMM1: z1 = relu(Xq @ W1^T + b1), M=32, N=128, K=768 ----
    // wave w: cols 16w..16w+15, M-subtiles {0,1}; B depth-4 register rotation.
    {
        f32x4 acc0 = {0.f, 0.f, 0.f, 0.f};
        f32x4 acc1 = {0.f, 0.f, 0.f, 0.f};
        const unsigned short* bp = W1b + (size_t)(16 * wid + l15) * 768 + l4 * 8;
        const int abase = l15 * 1536;
        const int aswz  = (l15 & 7) << 4;
        short8 breg[4];
#pragma unroll
        for (int i = 0; i < 4; ++i) breg[i] = *(const short8*)(bp + i * 32);

        for (int kt = 0; kt < 3; ++kt) {
            // stage 32 rows x 256 cols f32 -> bf16 LDS (2x 16B-chunks/thread)
            float4 va[2], vb[2];
            int rr[2], byo[2];
#pragma unroll
            for (int j = 0; j < 2; ++j) {
                int ci = tid + 512 * j;          // 0..1023
                int r  = ci >> 5, cc = ci & 31;
                rr[j] = r;
                byo[j] = (r * 1536 + kt * 512 + cc * 16) ^ ((r & 7) << 4);
                const float* p = X + (size_t)(row0 + r) * 2304 + kt * 256 + cc * 8;
                va[j] = *(const float4*)(p);
                vb[j] = *(const float4*)(p + 4);
            }
#pragma unroll
            for (int j = 0; j < 2; ++j) {
                uint4 u;
                u.x = pack2(va[j].x, va[j].y);
                u.y = pack2(va[j].z, va[j].w);
                u.z = pack2(vb[j].x, vb[j].y);
                u.w = pack2(vb[j].z, vb[j].w);
                *(uint4*)(xq + byo[j]) = u;
            }
            __syncthreads();
#pragma unroll
            for (int k = 0; k < 8; ++k) {
                const int it = kt * 8 + k;
                const int k0 = it * 32;
                short8 b = breg[it & 3];
                short8 a0 = *(const short8*)(xq + ((abase + (k0 + l4 * 8) * 2) ^ aswz));
                short8 a1 = *(const short8*)(xq + ((abase + 16 * 1536 + (k0 + l4 * 8) * 2) ^ aswz));
                acc0 = __builtin_amdgcn_mfma_f32_16x16x32_bf16(a0, b, acc0, 0, 0, 0);
                acc1 = __builtin_amdgcn_mfma_f32_16x16x32_bf16(a1, b, acc1, 0, 0, 0);
                if (it < 20) breg[it & 3] = *(const short8*)(bp + (it + 4) * 32);
            }
            __syncthreads();  // before next stage overwrites xq
        }
        float bv = b1[16 * wid + l15];
#pragma unroll
        for (int r = 0; r < 4; ++r) {
            float v0 = fmaxf(acc0[r] + bv, 0.f);
            float v1 = fmaxf(acc1[r] + bv, 0.f);
            z1[4 * l4 + r][16 * wid + l15]      = (unsigned short)(bfhi(v0) >> 16);
            z1[16 + 4 * l4 + r][16 * wid + l15] = (unsigned short)(bfhi(v1) >> 16);
        }
    }
    __syncthreads();

    // ---- GEMM2: z2 = relu(z1 @ W2^T + b2), M=32, N=64, K=128 ----
    // 8 waves: ms = wid&1 (M-subtile), nh = wid>>1 (16-col group)
    {
        const int ms = wid & 1, nh = wid >> 1;
        f32x4 acc = {0.f, 0.f, 0.f, 0.f};
        const unsigned short* bp = W2b + (size_t)(16 * nh + l15) * 128 + l4 * 8;
#pragma unroll
        for (int ks = 0; ks < 4; ++ks) {
            short8 a = *(const short8*)&z1[16 * ms + l15][ks * 32 + l4 * 8];
            short8 b = *(const short8*)(bp + ks * 32);
            acc = __builtin_amdgcn_mfma_f32_16x16x32_bf16(a, b, acc, 0, 0, 0);
        }
        float bv = b2[16 * nh + l15];
#pragma unroll
        for (int r = 0; r < 4; ++r) {
            float v = fmaxf(acc[r] + bv, 0.f);
            z2[16 * ms + 4 * l4 + r][16 * nh + l15] = (unsigned short)(bfhi(v) >> 16);
        }
    }
    __syncthreads();

    // ---- GEMM3: z3 = relu(z2 @ W3^T + b3), M=32, N=32, K=64; s=||z3||^2 ----
    // waves 0-3: ms = wid&1, gg = wid>>1
    if (wid < 4) {
        const int ms = wid & 1, gg = wid >> 1;
        f32x4 acc = {0.f, 0.f, 0.f, 0.f};
        const unsigned short* bp = W3b + (size_t)(16 * gg + l15) * 64 + l4 * 8;
#pragma unroll
        for (int ks = 0; ks < 2; ++ks) {
            short8 a = *(const short8*)&z2[16 * ms + l15][ks * 32 + l4 * 8];
            short8 b = *(const short8*)(bp + ks * 32);
            acc = __builtin_amdgcn_mfma_f32_16x16x32_bf16(a, b, acc, 0, 0, 0);
        }
        float bv = b3[16 * gg + l15];
        float sv[4];
#pragma unroll
        for (int r = 0; r < 4; ++r) {
            float v = fmaxf(acc[r] + bv, 0.f);
            sv[r] = v * v;
        }
#pragma unroll
        for (int m = 1; m < 16; m <<= 1)
#pragma unroll
            for (int r = 0; r < 4; ++r) sv[r] += __shfl_xor(sv[r], m);
        if (l15 == 0)
#pragma unroll
            for (int r = 0; r < 4; ++r) sred[gg][16 * ms + 4 * l4 + r] = sv[r];
    }
    __syncthreads();
    if (tid < 32) wsf[12288 + row0 + tid] = sred[0][tid] + sred[1][tid];
}

// K2: combine. out = s*d / max(s*sqrt(n1*n2), eps)
__global__ __launch_bounds__(512) void combine(
    const float* __restrict__ wsf, float* __restrict__ out)
{
    int i = blockIdx.x * 512 + threadIdx.x;
    float d  = wsf[i];
    float n1 = wsf[4096 + i];
    float n2 = wsf[8192 + i];
    float s  = wsf[12288 + i];
    out[i] = (s * d) / fmaxf(s * sqrtf(n1 * n2), 1e-8f);
}

extern "C" void kernel_launch(void* const* d_in, const int* in_sizes, int n_in,
                              void* d_out, int out_size, void* d_ws, size_t ws_size,
                              hipStream_t stream)
{
    (void)in_sizes; (void)n_in; (void)out_size; (void)ws_size;
    const float* X  = (const float*)d_in[0];
    const float* W1 = (const float*)d_in[1];
    const float* b1 = (const float*)d_in[2];
    const float* W2 = (const float*)d_in[3];
    const float* b2 = (const float*)d_in[4];
    const float* W3 = (const float*)d_in[5];
    const float* b3 = (const float*)d_in[6];

    float* wsf          = (float*)d_ws;                   // d, n1, n2, s (4x4096)
    unsigned short* wsb = (unsigned short*)(wsf + 16384); // bf16 weights

    cvt_weights<<<dim3(106), dim3(256), 0, stream>>>(W1, W2, W3, wsb);
    pq_kernel<<<dim3(384), dim3(512), 0, stream>>>(X, wsb, b1, b2, b3, wsf);
    combine<<<dim3(8), dim3(512), 0, stream>>>(wsf, (float*)d_out);
}